// Round 12
// baseline (209.654 us; speedup 1.0000x reference)
//
#include <hip/hip_runtime.h>
#include <hip/hip_fp16.h>

#define D 128
#define BLOCK 256      // K2 block
#define BLOCK1 1024    // K1 block (16 waves)
#define CAP 96         // deg ~ Poisson(32); P(deg>96)*N ~ 1e-15 -> safe
#define NPB 32         // nodes per fine bin / K2 block
#define NPBSH 5
#define NFBW 2048      // offtab row width (>= 1563 fine bins + sentinel headroom)
#define CHUNK 8192     // edges per bin block -> 196 bin blocks

typedef __attribute__((ext_vector_type(2))) float floatx2;
typedef __attribute__((ext_vector_type(4))) float floatx4;
typedef __attribute__((ext_vector_type(8))) _Float16 half8;

union U4H8 { uint4 u; half8 h; };

__device__ inline void addq(float* acc, unsigned int q) {
    floatx2 lo = __builtin_amdgcn_cvt_pk_f32_fp8(q, false);
    floatx2 hi = __builtin_amdgcn_cvt_pk_f32_fp8(q, true);
    acc[0] += lo[0]; acc[1] += lo[1]; acc[2] += hi[0]; acc[3] += hi[1];
}

__device__ inline void add16(float* acc, uint4 r) {
    addq(acc + 0,  r.x);
    addq(acc + 4,  r.y);
    addq(acc + 8,  r.z);
    addq(acc + 12, r.w);
}

// ---------------------------------------------------------------------------
// r12 K1: UNCHANGED from r11 (per-block LDS counting sort; ~53us est).
// ---------------------------------------------------------------------------
__global__ __launch_bounds__(BLOCK1) void sage_prep_binsort(
    const int* __restrict__ src, const int* __restrict__ dst,
    unsigned int* __restrict__ bins2, int* __restrict__ offtab, int n_edges,
    int nbin_blocks,
    const float4* __restrict__ feat4, unsigned int* __restrict__ feat8, int n4,
    int ncvt_blocks,
    const float* __restrict__ W_self, const float* __restrict__ W_neigh,
    const float* __restrict__ b_self, const float* __restrict__ b_neigh,
    unsigned int* __restrict__ wcat2, float* __restrict__ biascat)
{
    __shared__ unsigned int items[CHUNK];   // 32 KB
    __shared__ int hist[NFBW];              // 8 KB (becomes off[] in place)
    __shared__ int aux[BLOCK1];             // 4 KB
    int b = blockIdx.x, t = threadIdx.x;

    if (b < nbin_blocks) {
        hist[t] = 0; hist[t + 1024] = 0;
        __syncthreads();

        int e0 = b * CHUNK;
        int eend = min(e0 + CHUNK, n_edges);

        for (int i = e0 + t; i < eend; i += BLOCK1)
            atomicAdd(&hist[dst[i] >> NPBSH], 1);
        __syncthreads();

        int s0 = hist[2 * t], s1 = hist[2 * t + 1];
        int local = s0 + s1;
        aux[t] = local;
        __syncthreads();
        for (int dd = 1; dd < BLOCK1; dd <<= 1) {
            int v = (t >= dd) ? aux[t - dd] : 0;
            __syncthreads();
            aux[t] += v;
            __syncthreads();
        }
        int excl = aux[t] - local;
        hist[2 * t] = excl;
        hist[2 * t + 1] = excl + s0;
        __syncthreads();

        offtab[(size_t)b * NFBW + t]        = hist[t];
        offtab[(size_t)b * NFBW + 1024 + t] = hist[1024 + t];
        __syncthreads();

        for (int i = e0 + t; i < eend; i += BLOCK1) {
            int d = dst[i];
            int s = src[i];
            int pos = atomicAdd(&hist[d >> NPBSH], 1);
            items[pos] = ((unsigned int)(d & (NPB - 1)) << 16) | (unsigned int)s;
        }
        __syncthreads();

        uint4* gb = (uint4*)(bins2 + (size_t)b * CHUNK);
        const uint4* lb = (const uint4*)items;
        gb[t] = lb[t];
        gb[1024 + t] = lb[1024 + t];
    } else if (b < nbin_blocks + ncvt_blocks) {
        int i = (b - nbin_blocks) * BLOCK1 + t;
        if (i < n4) {
            float4 f = feat4[i];
            unsigned int r = __builtin_amdgcn_cvt_pk_fp8_f32(f.x, f.y, 0u, false);
            r = __builtin_amdgcn_cvt_pk_fp8_f32(f.z, f.w, r, true);
            feat8[i] = r;
        }
    } else {
        int idx = (b - nbin_blocks - ncvt_blocks) * BLOCK1 + t;   // 0..16383
        if (idx < 16384) {
            int n = idx >> 7;
            int k = (idx & 127) * 2;
            float a, bb;
            if (k < 128) { a = W_self[n * 128 + k];        bb = W_self[n * 128 + k + 1]; }
            else         { a = W_neigh[n * 128 + k - 128]; bb = W_neigh[n * 128 + k - 127]; }
            __half2 h = __floats2half2_rn(a, bb);
            wcat2[idx] = *reinterpret_cast<unsigned int*>(&h);
            if (idx < 128) biascat[idx] = b_self[idx] + b_neigh[idx];
        }
    }
}

// ---------------------------------------------------------------------------
// r12 K2: P2 and PB r11-verbatim. PA restructured for CROSS-NODE ILP:
// wave w processes its 8 nodes as 4 PAIRS (v, v+4), interleaving the two
// nodes' load epochs (8 independent feat8 loads in flight instead of 4;
// one ~700cy round trip amortized over two nodes). Rationale: K2's 88us is
// ~70us exposed latency (VALU-busy only ~18us); r2(TLP)/r4(global-bucket
// batching) nulled, but cross-node ILP with the LDS bucket is untried.
// Per-node edge summation order UNCHANGED -> bit-identical numerics.
// Cost: ~+40 VGPR (48 -> ~90; no min-wave launch_bounds cap -> no r1 spill).
// ---------------------------------------------------------------------------
__global__ __launch_bounds__(BLOCK) void sage_bucket_agg(
    const float* __restrict__ feat,
    const uint4* __restrict__ feat84,
    const unsigned int* __restrict__ bins2,
    const int* __restrict__ offtab,
    const uint4* __restrict__ wcat4,     // Wcat f16 [128][256] -> 32 uint4/row
    const float* __restrict__ biascat,
    float* __restrict__ out, int n_nodes, int nbin_blocks)
{
    __shared__ unsigned short buck[NPB * CAP];     // 6.0 KB
    __shared__ int cnt[NPB];
    __shared__ _Float16 mean_lds[NPB][136];        // 8.7 KB

    int b = blockIdx.x;
    int t = threadIdx.x;
    int wave = t >> 6;
    int lane = t & 63;

    // ---- P2: segment-gather LDS bucket build (r11-verbatim) ----
    if (t < NPB) cnt[t] = 0;
    __syncthreads();
    for (int s = t; s < nbin_blocks; s += BLOCK) {
        int o0 = offtab[(size_t)s * NFBW + b];
        int o1 = offtab[(size_t)s * NFBW + b + 1];
        const unsigned int* bp = bins2 + (size_t)s * CHUNK;
        for (int i = o0; i < o1; ++i) {
            unsigned int it = bp[i];
            int rel = (int)(it >> 16);
            int c = atomicAdd(&cnt[rel], 1);
            if (c < CAP) buck[rel * CAP + c] = (unsigned short)(it & 0xFFFFu);
        }
    }
    __syncthreads();

    int v0 = b * NPB;

    // ---- PA: gather + mean -> LDS, 2-node interleaved ----
    {
        int g = (lane >> 4) & 3;
        int eo = (lane >> 3) & 1;
        int h = lane & 7;
        int lo = 2 * g + eo;

        for (int v = wave; v < NPB; v += 8) {
            int va = v, vb = v + 4;
            int na = v0 + va, nb = v0 + vb;
            int hasA = (na < n_nodes), hasB = (nb < n_nodes);
            int degA = hasA ? cnt[va] : 0;
            int degB = hasB ? cnt[vb] : 0;
            int cvA = min(degA, CAP), cvB = min(degB, CAP);
            const unsigned short* bkA = &buck[va * CAP];
            const unsigned short* bkB = &buck[vb * CAP];

            float accA[16], accB[16];
            #pragma unroll
            for (int i = 0; i < 16; ++i) { accA[i] = 0.0f; accB[i] = 0.0f; }

            int eA = 0, eB = 0;
            while ((eA + 32 <= cvA) || (eB + 32 <= cvB)) {
                bool dA = (eA + 32 <= cvA);
                bool dB = (eB + 32 <= cvB);
                uint4 rA0, rA1, rA2, rA3, rB0, rB1, rB2, rB3;
                if (dA) {
                    int s0 = bkA[eA + lo];
                    int s1 = bkA[eA + 8 + lo];
                    int s2 = bkA[eA + 16 + lo];
                    int s3 = bkA[eA + 24 + lo];
                    rA0 = feat84[(size_t)s0 * 8 + h];
                    rA1 = feat84[(size_t)s1 * 8 + h];
                    rA2 = feat84[(size_t)s2 * 8 + h];
                    rA3 = feat84[(size_t)s3 * 8 + h];
                }
                if (dB) {
                    int s0 = bkB[eB + lo];
                    int s1 = bkB[eB + 8 + lo];
                    int s2 = bkB[eB + 16 + lo];
                    int s3 = bkB[eB + 24 + lo];
                    rB0 = feat84[(size_t)s0 * 8 + h];
                    rB1 = feat84[(size_t)s1 * 8 + h];
                    rB2 = feat84[(size_t)s2 * 8 + h];
                    rB3 = feat84[(size_t)s3 * 8 + h];
                }
                if (dA) {
                    add16(accA, rA0); add16(accA, rA1);
                    add16(accA, rA2); add16(accA, rA3);
                    eA += 32;
                }
                if (dB) {
                    add16(accB, rB0); add16(accB, rB1);
                    add16(accB, rB2); add16(accB, rB3);
                    eB += 32;
                }
            }
            // interleaved tails: issue all guarded loads (A then B), then adds
            {
                uint4 tA[4], tB[4];
                #pragma unroll
                for (int k = 0; k < 4; ++k) {
                    int idx = eA + 8 * k + lo;
                    if (idx < cvA) tA[k] = feat84[(size_t)bkA[idx] * 8 + h];
                }
                #pragma unroll
                for (int k = 0; k < 4; ++k) {
                    int idx = eB + 8 * k + lo;
                    if (idx < cvB) tB[k] = feat84[(size_t)bkB[idx] * 8 + h];
                }
                #pragma unroll
                for (int k = 0; k < 4; ++k) {
                    int idx = eA + 8 * k + lo;
                    if (idx < cvA) add16(accA, tA[k]);
                }
                #pragma unroll
                for (int k = 0; k < 4; ++k) {
                    int idx = eB + 8 * k + lo;
                    if (idx < cvB) add16(accB, tB[k]);
                }
            }

            #pragma unroll
            for (int i = 0; i < 16; ++i) {
                accA[i] += __shfl_xor(accA[i], 8);
                accA[i] += __shfl_xor(accA[i], 16);
                accA[i] += __shfl_xor(accA[i], 32);
                accB[i] += __shfl_xor(accB[i], 8);
                accB[i] += __shfl_xor(accB[i], 16);
                accB[i] += __shfl_xor(accB[i], 32);
            }
            if (lane < 8) {
                if (hasA) {
                    float inv = 1.0f / fmaxf((float)degA, 1.0f);
                    unsigned int p[8];
                    #pragma unroll
                    for (int i = 0; i < 8; ++i) {
                        __half2 hh = __floats2half2_rn(accA[2 * i] * inv, accA[2 * i + 1] * inv);
                        p[i] = *reinterpret_cast<unsigned int*>(&hh);
                    }
                    uint4 lo4 = { p[0], p[1], p[2], p[3] };
                    uint4 hi4 = { p[4], p[5], p[6], p[7] };
                    uint4* xp = (uint4*)&mean_lds[va][h * 16];
                    xp[0] = lo4;
                    xp[1] = hi4;
                }
                if (hasB) {
                    float inv = 1.0f / fmaxf((float)degB, 1.0f);
                    unsigned int p[8];
                    #pragma unroll
                    for (int i = 0; i < 8; ++i) {
                        __half2 hh = __floats2half2_rn(accB[2 * i] * inv, accB[2 * i + 1] * inv);
                        p[i] = *reinterpret_cast<unsigned int*>(&hh);
                    }
                    uint4 lo4 = { p[0], p[1], p[2], p[3] };
                    uint4 hi4 = { p[4], p[5], p[6], p[7] };
                    uint4* xp = (uint4*)&mean_lds[vb][h * 16];
                    xp[0] = lo4;
                    xp[1] = hi4;
                }
            }
        }
    }
    __syncthreads();

    // ---- PB: MFMA GEMM (r7-verbatim); wave w -> rowgroup w>>1, tiles (w&1)*4.. ----
    {
        int rg = wave >> 1;
        int ch = wave & 1;
        int m16 = lane & 15;
        int kq = lane >> 4;
        int m = v0 + rg * 16 + m16;
        int msafe = (m < n_nodes) ? m : 0;

        half8 a[8];
        const float4* fp = (const float4*)(feat + (size_t)msafe * D);
        #pragma unroll
        for (int kt = 0; kt < 4; ++kt) {
            float4 f0 = fp[kt * 8 + kq * 2];
            float4 f1 = fp[kt * 8 + kq * 2 + 1];
            half8 hh;
            hh[0] = (_Float16)f0.x; hh[1] = (_Float16)f0.y;
            hh[2] = (_Float16)f0.z; hh[3] = (_Float16)f0.w;
            hh[4] = (_Float16)f1.x; hh[5] = (_Float16)f1.y;
            hh[6] = (_Float16)f1.z; hh[7] = (_Float16)f1.w;
            a[kt] = hh;
        }
        const uint4* mrow = (const uint4*)&mean_lds[rg * 16 + m16][0];  // 17 uint4/row
        #pragma unroll
        for (int kt = 0; kt < 4; ++kt) {
            U4H8 u; u.u = mrow[kt * 4 + kq];
            a[4 + kt] = u.h;
        }

        #pragma unroll
        for (int cc = 0; cc < 4; ++cc) {
            int ct = ch * 4 + cc;
            floatx4 acc = { 0.f, 0.f, 0.f, 0.f };
            #pragma unroll
            for (int kt = 0; kt < 8; ++kt) {
                U4H8 w; w.u = wcat4[(size_t)(ct * 16 + m16) * 32 + kt * 4 + kq];
                acc = __builtin_amdgcn_mfma_f32_16x16x32_f16(a[kt], w.h, acc, 0, 0, 0);
            }
            float bias = biascat[ct * 16 + m16];
            #pragma unroll
            for (int i = 0; i < 4; ++i) {
                int r = v0 + rg * 16 + kq * 4 + i;
                if (r < n_nodes)
                    out[(size_t)r * D + ct * 16 + m16] = acc[i] + bias;
            }
        }
    }
}

extern "C" void kernel_launch(void* const* d_in, const int* in_sizes, int n_in,
                              void* d_out, int out_size, void* d_ws, size_t ws_size,
                              hipStream_t stream)
{
    const float* feat    = (const float*)d_in[0];
    const int*   src     = (const int*)d_in[1];
    const int*   dst     = (const int*)d_in[2];
    const float* W_self  = (const float*)d_in[3];
    const float* b_self  = (const float*)d_in[4];
    const float* W_neigh = (const float*)d_in[5];
    const float* b_neigh = (const float*)d_in[6];
    float* out = (float*)d_out;

    int n_nodes = in_sizes[0] / D;
    int n_edges = in_sizes[1];

    int nbinblk = (n_edges + CHUNK - 1) / CHUNK;     // 196

    // ws layout (~14.5 MB):
    //   bins2  u32[nbinblk*CHUNK]   6.42MB  (per-block sorted runs)
    //   offtab int[nbinblk*NFBW]    1.61MB  (per-block fine-bin offsets)
    //   feat8  u32[n*32]            6.40MB
    //   wcat   u32[128*128]         64KB
    //   biascat f32[128]
    unsigned int* bins2 = (unsigned int*)d_ws;
    int* offtab = (int*)(bins2 + (size_t)nbinblk * CHUNK);
    unsigned int* feat8 = (unsigned int*)(offtab + (size_t)nbinblk * NFBW);
    unsigned int* wcat = feat8 + (size_t)n_nodes * (D / 4);
    float* biascat = (float*)(wcat + 128 * 128);

    int n4 = n_nodes * (D / 4);
    int ncvt = (n4 + BLOCK1 - 1) / BLOCK1;           // 1563
    int nwcat = 16;                                  // 16384 / 1024
    int naggblk = (n_nodes + NPB - 1) / NPB;         // 1563

    sage_prep_binsort<<<nbinblk + ncvt + nwcat, BLOCK1, 0, stream>>>(
        src, dst, bins2, offtab, n_edges, nbinblk,
        (const float4*)feat, feat8, n4, ncvt,
        W_self, W_neigh, b_self, b_neigh, wcat, biascat);
    sage_bucket_agg<<<naggblk, BLOCK, 0, stream>>>(
        feat, (const uint4*)feat8, bins2, offtab,
        (const uint4*)wcat, biascat, out, n_nodes, nbinblk);
}